// Round 6
// baseline (23.929 us; speedup 1.0000x reference)
//
#include <hip/hip_runtime.h>
#include <math.h>

// JPEG layer: RGB->YCbCr, clip/shift, 2x2 chroma pool (sub-OFF after), 8x8 DCT,
// quantize, round. One 256-thread WG per 32x32 pixel tile; 16 Y + 4 Cb + 4 Cr
// 8x8 blocks per tile, one wave per block, 6 rounds of 4.
// Stage-2 of the DCT uses intra-wave shuffles (wave-private exchange) instead of
// an LDS round-trip: removes 12 of 14 __syncthreads per WG.

static __device__ __forceinline__ float clip01(float v) {
    return fminf(fmaxf(v, 0.0f), 1.0f);
}

__global__ __launch_bounds__(256)
void jpeg_kernel(const float* __restrict__ rgb, const float* __restrict__ quant,
                 float* __restrict__ out)
{
    // single shared block with integer offsets -> guaranteed ds_read/ds_write addressing
    __shared__ __align__(16) float smem[4096];
    constexpr int YT  = 0;     // y   [32][36]
    constexpr int CBF = 1152;  // cb  clipped, PRE-subtract [32][36]
    constexpr int CRF = 2304;  // cr  clipped, PRE-subtract [32][36]
    constexpr int CB8 = 3456;  // pooled cb [16][18]
    constexpr int CR8 = 3744;  // pooled cr [16][18]
    constexpr int DM  = 4032;  // DCT matrix [8][8]

    const int t = threadIdx.x;

    // DCT matrix in double (matches python math.cos path; sqrt(2/8) == 0.5 exactly)
    if (t < 64) {
        const int i = t >> 3, j = t & 7;
        double v;
        if (i == 0) v = 0.35355339059327373;           // 1/sqrt(8)
        else        v = 0.5 * cos(3.141592653589793 * (double)(2 * j + 1) * (double)i / 16.0);
        smem[DM + t] = (float)v;
    }

    const int wg   = blockIdx.x;
    const int b    = wg >> 8;         // image index (256 tiles per image)
    const int tile = wg & 255;
    const int th   = tile >> 4;       // tile row 0..15
    const int tw   = tile & 15;       // tile col 0..15

    // ---- color transform: 4 consecutive pixels per thread (float4 loads) ----
    {
        const int row = t >> 3;            // 0..31
        const int c4  = (t & 7) << 2;      // 0,4,...,28
        const float* p = rgb + ((size_t)b * 3) * 262144 + (size_t)(th * 32 + row) * 512 + (tw * 32 + c4);
        const float4 R  = *(const float4*)p;
        const float4 G  = *(const float4*)(p + 262144);
        const float4 Bv = *(const float4*)(p + 524288);
        const float OFF = (float)(128.0 / 255.0);
        const float rr[4] = {R.x, R.y, R.z, R.w};
        const float gg[4] = {G.x, G.y, G.z, G.w};
        const float bb[4] = {Bv.x, Bv.y, Bv.z, Bv.w};
        float yv[4], cbv[4], crv[4];
        #pragma unroll
        for (int k = 0; k < 4; ++k) {
            const float r_ = rr[k], g_ = gg[k], b_ = bb[k];
            const float y  = (float)(0.299) * r_ + (float)(0.587) * g_ + (float)(0.114) * b_;
            const float cb = (float)(-0.168735892) * r_ + (float)(-0.331264108) * g_ + 0.5f * b_;
            const float cr = 0.5f * r_ + (float)(-0.418687589) * g_ + (float)(-0.081312411) * b_;
            yv[k]  = clip01(y) - OFF;
            cbv[k] = clip01(cb + OFF);     // clipped, pre-subtract (subtract after pool)
            crv[k] = clip01(cr + OFF);
        }
        *(float4*)&smem[YT  + row * 36 + c4] = make_float4(yv[0], yv[1], yv[2], yv[3]);
        *(float4*)&smem[CBF + row * 36 + c4] = make_float4(cbv[0], cbv[1], cbv[2], cbv[3]);
        *(float4*)&smem[CRF + row * 36 + c4] = make_float4(crv[0], crv[1], crv[2], crv[3]);
    }
    __syncthreads();

    // ---- 2x2 chroma pooling (subtract OFF after the mean) ----
    {
        const float OFF = (float)(128.0 / 255.0);
        const int pr = t >> 4, pc = t & 15;
        const int o00 = (2 * pr) * 36 + 2 * pc;
        const int o10 = o00 + 36;
        float sb = smem[CBF + o00];
        sb = sb + smem[CBF + o00 + 1];
        sb = sb + smem[CBF + o10];
        sb = sb + smem[CBF + o10 + 1];
        smem[CB8 + pr * 18 + pc] = sb * 0.25f - OFF;
        const float cr_r0 = smem[CRF + o00] + smem[CRF + o00 + 1];
        const float cr_r1 = smem[CRF + o10] + smem[CRF + o10 + 1];
        smem[CR8 + pr * 18 + pc] = (cr_r0 + cr_r1) * 0.25f - OFF;
    }
    __syncthreads();

    // ---- DCT + quantize: one wave per 8x8 block, 6 rounds of 4 blocks ----
    // No block-wide sync needed below: tiles are read-only, stage-2 exchange is
    // intra-wave via __shfl (values & accumulation order identical to the LDS
    // round-trip version -> bit-exact).
    const int g = t >> 6;            // wave id 0..3
    const int r = (t >> 3) & 7;      // output row
    const int c = t & 7;             // output col
    const int lanebase = (t & 63) & 56;   // r*8 within wave
    float Dr[8], Dc[8];
    #pragma unroll
    for (int k = 0; k < 8; ++k) { Dr[k] = smem[DM + r * 8 + k]; Dc[k] = smem[DM + c * 8 + k]; }
    const int qi = r * 8 + c;
    const float qadd = (float)(0.5 / 255.0);
    // mul/add separately rounded (no FMA contraction) to match numpy
    const float den0 = __fadd_rn(__fmul_rn(quant[qi],        2.5f), qadd);
    const float den1 = __fadd_rn(__fmul_rn(quant[64 + qi],   2.5f), qadd);
    const float den2 = __fadd_rn(__fmul_rn(quant[128 + qi],  2.5f), qadd);

    #pragma unroll
    for (int it = 0; it < 6; ++it) {
        const int sb = it * 4 + g;       // sub-block 0..23, uniform per wave
        int xoff, ldx; size_t oidx; float den;
        if (sb < 16) {                   // Y blocks: 4x4 grid of 8x8 within the 32x32 tile
            const int sr = sb >> 2, sc = sb & 3;
            xoff = YT + sr * 8 * 36 + sc * 8; ldx = 36;
            const int bh = th * 4 + sr, bw = tw * 4 + sc;     // block coords in 64x64
            oidx = (((size_t)(b * 64 + bh)) * 64 + bw) * 64 + (r * 8 + c);
            den = den0;
        } else if (sb < 20) {            // Cb blocks: 2x2 grid of 8x8 within pooled 16x16
            const int s = sb - 16, sr = s >> 1, sc = s & 1;
            xoff = CB8 + sr * 8 * 18 + sc * 8; ldx = 18;
            const int bh = th * 2 + sr, bw = tw * 2 + sc;     // block coords in 32x32
            oidx = (size_t)4194304 + (((size_t)(b * 32 + bh)) * 32 + bw) * 64 + (r * 8 + c);
            den = den1;
        } else {                         // Cr blocks
            const int s = sb - 20, sr = s >> 1, sc = s & 1;
            xoff = CR8 + sr * 8 * 18 + sc * 8; ldx = 18;
            const int bh = th * 2 + sr, bw = tw * 2 + sc;
            oidx = (size_t)5242880 + (((size_t)(b * 32 + bh)) * 32 + bw) * 64 + (r * 8 + c);
            den = den2;
        }
        // stage 1: tmp[r][c] = sum_j D[r][j] * X[j][c]   (broadcast LDS reads)
        float s1 = 0.0f;
        #pragma unroll
        for (int j = 0; j < 8; ++j) s1 += Dr[j] * smem[xoff + j * ldx + c];
        // stage 2: out[r][c] = sum_k tmp[r][k] * D[c][k]; tmp[r][k] lives in
        // lane (r*8+k) of this wave -> 8 ds_bpermute, no barrier.
        float s2 = 0.0f;
        #pragma unroll
        for (int k = 0; k < 8; ++k) {
            const float tk = __shfl(s1, lanebase + k, 64);
            s2 += tk * Dc[k];
        }
        out[oidx] = rintf(s2 / den);     // rintf = round half to even, matches jnp/np.round
    }
}

extern "C" void kernel_launch(void* const* d_in, const int* in_sizes, int n_in,
                              void* d_out, int out_size, void* d_ws, size_t ws_size,
                              hipStream_t stream) {
    const float* rgb   = (const float*)d_in[0];
    const float* quant = (const float*)d_in[1];
    float* out = (float*)d_out;
    dim3 grid(4096), block(256);
    hipLaunchKernelGGL(jpeg_kernel, grid, block, 0, stream, rgb, quant, out);
}

// Round 7
// 21.150 us; speedup vs baseline: 1.1314x; 1.1314x over previous
//
#include <hip/hip_runtime.h>
#include <math.h>

// JPEG layer: RGB->YCbCr, clip/shift, 2x2 chroma pool (sub-OFF after), 8x8 DCT,
// quantize, round. One 256-thread WG per 32x32 pixel tile; 16 Y + 4 Cb + 4 Cr
// 8x8 blocks per tile, one wave per block, 6 rounds of 4.
// The TMP exchange in the DCT is wave-private LDS (g-indexed region): no
// block-wide barrier needed -> only 2 __syncthreads per WG (structural).
// (Round-6 lesson: ds_bpermute exchange costs MORE LDS-pipe ops than the
// 1-write + 8-broadcast-read round-trip; keep the round-trip.)

static __device__ __forceinline__ float clip01(float v) {
    return fminf(fmaxf(v, 0.0f), 1.0f);
}

__global__ __launch_bounds__(256)
void jpeg_kernel(const float* __restrict__ rgb, const float* __restrict__ quant,
                 float* __restrict__ out)
{
    // single shared block with integer offsets -> guaranteed ds_read/ds_write addressing
    __shared__ __align__(16) float smem[4384];
    constexpr int YT  = 0;     // y   [32][36]
    constexpr int CBF = 1152;  // cb  clipped, PRE-subtract [32][36]
    constexpr int CRF = 2304;  // cr  clipped, PRE-subtract [32][36]
    constexpr int CB8 = 3456;  // pooled cb [16][18]
    constexpr int CR8 = 3744;  // pooled cr [16][18]
    constexpr int DM  = 4032;  // DCT matrix [8][8]
    constexpr int TMP = 4096;  // per-wave tmp [4][8][9] — wave-private!

    const int t = threadIdx.x;

    // DCT matrix in double (matches python math.cos path; sqrt(2/8) == 0.5 exactly)
    if (t < 64) {
        const int i = t >> 3, j = t & 7;
        double v;
        if (i == 0) v = 0.35355339059327373;           // 1/sqrt(8)
        else        v = 0.5 * cos(3.141592653589793 * (double)(2 * j + 1) * (double)i / 16.0);
        smem[DM + t] = (float)v;
    }

    const int wg   = blockIdx.x;
    const int b    = wg >> 8;         // image index (256 tiles per image)
    const int tile = wg & 255;
    const int th   = tile >> 4;       // tile row 0..15
    const int tw   = tile & 15;       // tile col 0..15

    // ---- color transform: 4 consecutive pixels per thread (float4 loads) ----
    {
        const int row = t >> 3;            // 0..31
        const int c4  = (t & 7) << 2;      // 0,4,...,28
        const float* p = rgb + ((size_t)b * 3) * 262144 + (size_t)(th * 32 + row) * 512 + (tw * 32 + c4);
        const float4 R  = *(const float4*)p;
        const float4 G  = *(const float4*)(p + 262144);
        const float4 Bv = *(const float4*)(p + 524288);
        const float OFF = (float)(128.0 / 255.0);
        const float rr[4] = {R.x, R.y, R.z, R.w};
        const float gg[4] = {G.x, G.y, G.z, G.w};
        const float bb[4] = {Bv.x, Bv.y, Bv.z, Bv.w};
        float yv[4], cbv[4], crv[4];
        #pragma unroll
        for (int k = 0; k < 4; ++k) {
            const float r_ = rr[k], g_ = gg[k], b_ = bb[k];
            const float y  = (float)(0.299) * r_ + (float)(0.587) * g_ + (float)(0.114) * b_;
            const float cb = (float)(-0.168735892) * r_ + (float)(-0.331264108) * g_ + 0.5f * b_;
            const float cr = 0.5f * r_ + (float)(-0.418687589) * g_ + (float)(-0.081312411) * b_;
            yv[k]  = clip01(y) - OFF;
            cbv[k] = clip01(cb + OFF);     // clipped, pre-subtract (subtract after pool)
            crv[k] = clip01(cr + OFF);
        }
        *(float4*)&smem[YT  + row * 36 + c4] = make_float4(yv[0], yv[1], yv[2], yv[3]);
        *(float4*)&smem[CBF + row * 36 + c4] = make_float4(cbv[0], cbv[1], cbv[2], cbv[3]);
        *(float4*)&smem[CRF + row * 36 + c4] = make_float4(crv[0], crv[1], crv[2], crv[3]);
    }
    __syncthreads();

    // ---- 2x2 chroma pooling (subtract OFF after the mean) ----
    {
        const float OFF = (float)(128.0 / 255.0);
        const int pr = t >> 4, pc = t & 15;
        const int o00 = (2 * pr) * 36 + 2 * pc;
        const int o10 = o00 + 36;
        float sb = smem[CBF + o00];
        sb = sb + smem[CBF + o00 + 1];
        sb = sb + smem[CBF + o10];
        sb = sb + smem[CBF + o10 + 1];
        smem[CB8 + pr * 18 + pc] = sb * 0.25f - OFF;
        const float cr_r0 = smem[CRF + o00] + smem[CRF + o00 + 1];
        const float cr_r1 = smem[CRF + o10] + smem[CRF + o10 + 1];
        smem[CR8 + pr * 18 + pc] = (cr_r0 + cr_r1) * 0.25f - OFF;
    }
    __syncthreads();

    // ---- DCT + quantize: one wave per 8x8 block, 6 rounds of 4 blocks ----
    // TMP region is per-wave: intra-wave LDS RAW is ordered by lgkmcnt (DS ops
    // of one wave complete in order) -> NO __syncthreads inside this loop.
    const int g = t >> 6;            // wave id 0..3
    const int r = (t >> 3) & 7;      // output row
    const int c = t & 7;             // output col
    float Dr[8], Dc[8];
    #pragma unroll
    for (int k = 0; k < 8; ++k) { Dr[k] = smem[DM + r * 8 + k]; Dc[k] = smem[DM + c * 8 + k]; }
    const int qi = r * 8 + c;
    const float qadd = (float)(0.5 / 255.0);
    // mul/add separately rounded (no FMA contraction) to match numpy
    const float den0 = __fadd_rn(__fmul_rn(quant[qi],        2.5f), qadd);
    const float den1 = __fadd_rn(__fmul_rn(quant[64 + qi],   2.5f), qadd);
    const float den2 = __fadd_rn(__fmul_rn(quant[128 + qi],  2.5f), qadd);

    #pragma unroll
    for (int it = 0; it < 6; ++it) {
        const int sb = it * 4 + g;       // sub-block 0..23, uniform per wave
        int xoff, ldx; size_t oidx; float den;
        if (sb < 16) {                   // Y blocks: 4x4 grid of 8x8 within the 32x32 tile
            const int sr = sb >> 2, sc = sb & 3;
            xoff = YT + sr * 8 * 36 + sc * 8; ldx = 36;
            const int bh = th * 4 + sr, bw = tw * 4 + sc;     // block coords in 64x64
            oidx = (((size_t)(b * 64 + bh)) * 64 + bw) * 64 + (r * 8 + c);
            den = den0;
        } else if (sb < 20) {            // Cb blocks: 2x2 grid of 8x8 within pooled 16x16
            const int s = sb - 16, sr = s >> 1, sc = s & 1;
            xoff = CB8 + sr * 8 * 18 + sc * 8; ldx = 18;
            const int bh = th * 2 + sr, bw = tw * 2 + sc;     // block coords in 32x32
            oidx = (size_t)4194304 + (((size_t)(b * 32 + bh)) * 32 + bw) * 64 + (r * 8 + c);
            den = den1;
        } else {                         // Cr blocks
            const int s = sb - 20, sr = s >> 1, sc = s & 1;
            xoff = CR8 + sr * 8 * 18 + sc * 8; ldx = 18;
            const int bh = th * 2 + sr, bw = tw * 2 + sc;
            oidx = (size_t)5242880 + (((size_t)(b * 32 + bh)) * 32 + bw) * 64 + (r * 8 + c);
            den = den2;
        }
        // stage 1: tmp[r][c] = sum_j D[r][j] * X[j][c]   (broadcast LDS reads)
        float s1 = 0.0f;
        #pragma unroll
        for (int j = 0; j < 8; ++j) s1 += Dr[j] * smem[xoff + j * ldx + c];
        // wave-private exchange: write then read within the same wave; the
        // compiler's lgkmcnt waits order the RAW. No block barrier.
        smem[TMP + g * 72 + r * 9 + c] = s1;
        // stage 2: out[r][c] = sum_k tmp[r][k] * D[c][k]
        float s2 = 0.0f;
        #pragma unroll
        for (int k = 0; k < 8; ++k) s2 += smem[TMP + g * 72 + r * 9 + k] * Dc[k];
        out[oidx] = rintf(s2 / den);     // rintf = round half to even, matches jnp/np.round
    }
}

extern "C" void kernel_launch(void* const* d_in, const int* in_sizes, int n_in,
                              void* d_out, int out_size, void* d_ws, size_t ws_size,
                              hipStream_t stream) {
    const float* rgb   = (const float*)d_in[0];
    const float* quant = (const float*)d_in[1];
    float* out = (float*)d_out;
    dim3 grid(4096), block(256);
    hipLaunchKernelGGL(jpeg_kernel, grid, block, 0, stream, rgb, quant, out);
}

// Round 8
// 18.055 us; speedup vs baseline: 1.3254x; 1.1714x over previous
//
#include <hip/hip_runtime.h>
#include <math.h>

// JPEG layer: RGB->YCbCr, clip/shift, 2x2 chroma pool (sub-OFF after), 8x8 DCT,
// quantize, round. One 256-thread WG per 32x32 pixel tile; 24 8x8 blocks/tile.
// DCT: 8 threads per block. Stage 1: thread owns column c (T = D*X, D as
// compile-time constants). Stage 2: thread owns row r=c of T (2x ds_read_b128),
// computes 8 outputs, 2x global_store_dwordx4. One pass, ~20 LDS wave-instrs
// per wave (was 102 over 6 iterations), 1 intra-wave RAW chain (was 6).
// TMP overlays the dead CBF/CRF region after pooling.

static __device__ __forceinline__ float clip01(float v) {
    return fminf(fmaxf(v, 0.0f), 1.0f);
}

// DCT-II 8x8 matrix as compile-time f32 constants: f32(0.5*cos(k*pi/16)).
// Row 0 = 1/sqrt(8), which equals M4 bitwise in f32.
#define M1f 0.49039264020161522f
#define M2f 0.46193976625564337f
#define M3f 0.41573480615127262f
#define M4f 0.35355339059327376f
#define M5f 0.27778511650980111f
#define M6f 0.19134171618254489f
#define M7f 0.097545161008064134f

static constexpr float Dm[8][8] = {
    { M4f,  M4f,  M4f,  M4f,  M4f,  M4f,  M4f,  M4f},
    { M1f,  M3f,  M5f,  M7f, -M7f, -M5f, -M3f, -M1f},
    { M2f,  M6f, -M6f, -M2f, -M2f, -M6f,  M6f,  M2f},
    { M3f, -M7f, -M1f, -M5f,  M5f,  M1f,  M7f, -M3f},
    { M4f, -M4f, -M4f,  M4f,  M4f, -M4f, -M4f,  M4f},
    { M5f, -M1f,  M7f,  M3f, -M3f, -M7f,  M1f, -M5f},
    { M6f, -M2f,  M2f, -M6f, -M6f,  M2f, -M2f,  M6f},
    { M7f, -M5f,  M3f, -M1f,  M1f, -M3f,  M5f, -M7f},
};

__global__ __launch_bounds__(256)
void jpeg_kernel(const float* __restrict__ rgb, const float* __restrict__ quant,
                 float* __restrict__ out)
{
    // single shared block with integer offsets -> guaranteed ds addressing
    __shared__ __align__(16) float smem[4224];
    constexpr int YT  = 0;     // y   [32][36]
    constexpr int CBF = 1152;  // cb  clipped, PRE-subtract [32][36]  (dead after pool)
    constexpr int CRF = 2304;  // cr  clipped, PRE-subtract [32][36]  (dead after pool)
    constexpr int TMP = 1152;  // DCT temp, overlays CBF/CRF: 4 waves * 6 blocks * 68
    constexpr int CB8 = 3456;  // pooled cb [16][18]
    constexpr int CR8 = 3744;  // pooled cr [16][18]
    constexpr int QNT = 4032;  // quant [3][64]

    const int t = threadIdx.x;

    // stage quant into LDS (covered by the first barrier)
    if (t < 192) smem[QNT + t] = quant[t];

    const int wg   = blockIdx.x;
    const int b    = wg >> 8;         // image index (256 tiles per image)
    const int tile = wg & 255;
    const int th   = tile >> 4;       // tile row 0..15
    const int tw   = tile & 15;       // tile col 0..15

    // ---- color transform: 4 consecutive pixels per thread (float4 loads) ----
    {
        const int row = t >> 3;            // 0..31
        const int c4  = (t & 7) << 2;      // 0,4,...,28
        const float* p = rgb + ((size_t)b * 3) * 262144 + (size_t)(th * 32 + row) * 512 + (tw * 32 + c4);
        const float4 R  = *(const float4*)p;
        const float4 G  = *(const float4*)(p + 262144);
        const float4 Bv = *(const float4*)(p + 524288);
        const float OFF = (float)(128.0 / 255.0);
        const float rr[4] = {R.x, R.y, R.z, R.w};
        const float gg[4] = {G.x, G.y, G.z, G.w};
        const float bb[4] = {Bv.x, Bv.y, Bv.z, Bv.w};
        float yv[4], cbv[4], crv[4];
        #pragma unroll
        for (int k = 0; k < 4; ++k) {
            const float r_ = rr[k], g_ = gg[k], b_ = bb[k];
            const float y  = (float)(0.299) * r_ + (float)(0.587) * g_ + (float)(0.114) * b_;
            const float cb = (float)(-0.168735892) * r_ + (float)(-0.331264108) * g_ + 0.5f * b_;
            const float cr = 0.5f * r_ + (float)(-0.418687589) * g_ + (float)(-0.081312411) * b_;
            yv[k]  = clip01(y) - OFF;
            cbv[k] = clip01(cb + OFF);     // clipped, pre-subtract (subtract after pool)
            crv[k] = clip01(cr + OFF);
        }
        *(float4*)&smem[YT  + row * 36 + c4] = make_float4(yv[0], yv[1], yv[2], yv[3]);
        *(float4*)&smem[CBF + row * 36 + c4] = make_float4(cbv[0], cbv[1], cbv[2], cbv[3]);
        *(float4*)&smem[CRF + row * 36 + c4] = make_float4(crv[0], crv[1], crv[2], crv[3]);
    }
    __syncthreads();

    // ---- 2x2 chroma pooling (subtract OFF after the mean) ----
    {
        const float OFF = (float)(128.0 / 255.0);
        const int pr = t >> 4, pc = t & 15;
        const int o00 = (2 * pr) * 36 + 2 * pc;
        const int o10 = o00 + 36;
        float sb = smem[CBF + o00];
        sb = sb + smem[CBF + o00 + 1];
        sb = sb + smem[CBF + o10];
        sb = sb + smem[CBF + o10 + 1];
        smem[CB8 + pr * 18 + pc] = sb * 0.25f - OFF;
        const float cr_r0 = smem[CRF + o00] + smem[CRF + o00 + 1];
        const float cr_r1 = smem[CRF + o10] + smem[CRF + o10 + 1];
        smem[CR8 + pr * 18 + pc] = (cr_r0 + cr_r1) * 0.25f - OFF;
    }
    __syncthreads();
    // CBF/CRF are dead from here; TMP overlays them.

    // ---- DCT + quantize: 8 threads per 8x8 block, one pass ----
    const int w  = t >> 6;           // wave 0..3
    const int l  = t & 63;
    const int bi = l >> 3;           // block-in-wave 0..5 (6,7 idle)
    const int lc = l & 7;            // stage-1 column / stage-2 row

    if (bi < 6) {
        const int sb = w * 6 + bi;   // block 0..23
        int xoff, ldx, ch; size_t obase;
        if (sb < 16) {               // Y: 4x4 grid of 8x8 in the 32x32 tile
            const int sr = sb >> 2, sc = sb & 3;
            xoff = YT + sr * 288 + sc * 8; ldx = 36; ch = 0;
            obase = (((size_t)(b * 64 + th * 4 + sr)) * 64 + (tw * 4 + sc)) * 64;
        } else if (sb < 20) {        // Cb: 2x2 grid in pooled 16x16
            const int s = sb - 16, sr = s >> 1, sc = s & 1;
            xoff = CB8 + sr * 144 + sc * 8; ldx = 18; ch = 1;
            obase = (size_t)4194304 + (((size_t)(b * 32 + th * 2 + sr)) * 32 + (tw * 2 + sc)) * 64;
        } else {                     // Cr
            const int s = sb - 20, sr = s >> 1, sc = s & 1;
            xoff = CR8 + sr * 144 + sc * 8; ldx = 18; ch = 2;
            obase = (size_t)5242880 + (((size_t)(b * 32 + th * 2 + sr)) * 32 + (tw * 2 + sc)) * 64;
        }

        // stage 1: thread owns column lc; T[i] = sum_j D[i][j] * X[j][lc]
        // (same j-ascending fmac chain as the bit-exact kernel)
        float x[8];
        #pragma unroll
        for (int j = 0; j < 8; ++j) x[j] = smem[xoff + j * ldx + lc];
        const int tbase = TMP + w * 408 + bi * 68;   // 68-dword pad: bank-spread, 16B-aligned
        #pragma unroll
        for (int i = 0; i < 8; ++i) {
            float s = 0.0f;
            #pragma unroll
            for (int j = 0; j < 8; ++j) s += Dm[i][j] * x[j];
            smem[tbase + i * 8 + lc] = s;
        }

        // stage 2: thread owns row lc of T (written by all 8 column-threads of
        // this block; intra-wave LDS ops complete in order -> no barrier,
        // validated bit-exact by the round-7 kernel's identical pattern).
        float tr[8], q[8];
        *(float4*)&tr[0] = *(const float4*)&smem[tbase + lc * 8];
        *(float4*)&tr[4] = *(const float4*)&smem[tbase + lc * 8 + 4];
        *(float4*)&q[0]  = *(const float4*)&smem[QNT + ch * 64 + lc * 8];
        *(float4*)&q[4]  = *(const float4*)&smem[QNT + ch * 64 + lc * 8 + 4];

        const float qadd = (float)(0.5 / 255.0);
        float o[8];
        #pragma unroll
        for (int cc = 0; cc < 8; ++cc) {
            float s = 0.0f;
            #pragma unroll
            for (int k = 0; k < 8; ++k) s += tr[k] * Dm[cc][k];   // k-ascending, as before
            const float den = __fadd_rn(__fmul_rn(q[cc], 2.5f), qadd);
            o[cc] = rintf(s / den);      // IEEE div + round-half-even, matches np
        }
        float* op = out + obase + lc * 8;
        *(float4*)&op[0] = make_float4(o[0], o[1], o[2], o[3]);
        *(float4*)&op[4] = make_float4(o[4], o[5], o[6], o[7]);
    }
}

extern "C" void kernel_launch(void* const* d_in, const int* in_sizes, int n_in,
                              void* d_out, int out_size, void* d_ws, size_t ws_size,
                              hipStream_t stream) {
    const float* rgb   = (const float*)d_in[0];
    const float* quant = (const float*)d_in[1];
    float* out = (float*)d_out;
    dim3 grid(4096), block(256);
    hipLaunchKernelGGL(jpeg_kernel, grid, block, 0, stream, rgb, quant, out);
}

// Round 9
// 17.968 us; speedup vs baseline: 1.3318x; 1.0048x over previous
//
#include <hip/hip_runtime.h>
#include <math.h>

// JPEG layer: RGB->YCbCr, clip/shift, 2x2 chroma pool (sub-OFF after), 8x8 DCT,
// quantize, round. One 256-thread WG per 32x32 pixel tile; 24 8x8 blocks/tile.
// Round-9 structure: each thread owns a 2x2 pixel quad -> pooling happens in
// registers (no CBF/CRF tiles, no pool pass, one barrier total). Y and pooled
// chroma are stored TRANSPOSED ([col][row], strides 36/20) so DCT stage-1
// column reads are 2x ds_read_b128. DCT: 8 threads per 8x8 block (stage 1
// column-owner -> TMP -> stage 2 row-owner), as validated in round 8.

static __device__ __forceinline__ float clip01(float v) {
    return fminf(fmaxf(v, 0.0f), 1.0f);
}

// DCT-II 8x8 matrix as compile-time f32 constants: f32(0.5*cos(k*pi/16)).
// Row 0 = 1/sqrt(8), which equals M4 bitwise in f32.
#define M1f 0.49039264020161522f
#define M2f 0.46193976625564337f
#define M3f 0.41573480615127262f
#define M4f 0.35355339059327376f
#define M5f 0.27778511650980111f
#define M6f 0.19134171618254489f
#define M7f 0.097545161008064134f

static constexpr float Dm[8][8] = {
    { M4f,  M4f,  M4f,  M4f,  M4f,  M4f,  M4f,  M4f},
    { M1f,  M3f,  M5f,  M7f, -M7f, -M5f, -M3f, -M1f},
    { M2f,  M6f, -M6f, -M2f, -M2f, -M6f,  M6f,  M2f},
    { M3f, -M7f, -M1f, -M5f,  M5f,  M1f,  M7f, -M3f},
    { M4f, -M4f, -M4f,  M4f,  M4f, -M4f, -M4f,  M4f},
    { M5f, -M1f,  M7f,  M3f, -M3f, -M7f,  M1f, -M5f},
    { M6f, -M2f,  M2f, -M6f, -M6f,  M2f, -M2f,  M6f},
    { M7f, -M5f,  M3f, -M1f,  M1f, -M3f,  M5f, -M7f},
};

__global__ __launch_bounds__(256)
void jpeg_kernel(const float* __restrict__ rgb, const float* __restrict__ quant,
                 float* __restrict__ out)
{
    // single shared block with integer offsets -> guaranteed ds addressing
    __shared__ __align__(16) float smem[3616];
    constexpr int YTT = 0;     // transposed Y [32 cols][36]
    constexpr int CBT = 1152;  // transposed pooled cb [16 cols][20]
    constexpr int CRT = 1472;  // transposed pooled cr [16 cols][20]
    constexpr int QNT = 1792;  // quant [3][64]
    constexpr int TMP = 1984;  // DCT temp: 4 waves * 6 blocks * 68

    const int t = threadIdx.x;

    // stage quant into LDS (covered by the barrier)
    if (t < 192) smem[QNT + t] = quant[t];

    const int wg   = blockIdx.x;
    const int b    = wg >> 8;         // image index (256 tiles per image)
    const int tile = wg & 255;
    const int th   = tile >> 4;       // tile row 0..15
    const int tw   = tile & 15;       // tile col 0..15

    // ---- color transform + in-register 2x2 pooling: one quad per thread ----
    {
        const int qr = t >> 4;             // quad row 0..15
        const int qc = t & 15;             // quad col 0..15
        const int r0 = 2 * qr, c0 = 2 * qc;
        const float* p = rgb + ((size_t)b * 3) * 262144 + (size_t)(th * 32 + r0) * 512 + (tw * 32 + c0);
        const float2 R0 = *(const float2*)p;
        const float2 R1 = *(const float2*)(p + 512);
        const float2 G0 = *(const float2*)(p + 262144);
        const float2 G1 = *(const float2*)(p + 262144 + 512);
        const float2 B0 = *(const float2*)(p + 524288);
        const float2 B1 = *(const float2*)(p + 524288 + 512);
        const float OFF = (float)(128.0 / 255.0);
        // order: 0=(r0,c0)=w00, 1=(r0,c1)=w01, 2=(r1,c0)=w10, 3=(r1,c1)=w11
        const float rr[4] = {R0.x, R0.y, R1.x, R1.y};
        const float gg[4] = {G0.x, G0.y, G1.x, G1.y};
        const float bb[4] = {B0.x, B0.y, B1.x, B1.y};
        float yv[4], cbv[4], crv[4];
        #pragma unroll
        for (int k = 0; k < 4; ++k) {
            const float r_ = rr[k], g_ = gg[k], b_ = bb[k];
            const float y  = (float)(0.299) * r_ + (float)(0.587) * g_ + (float)(0.114) * b_;
            const float cb = (float)(-0.168735892) * r_ + (float)(-0.331264108) * g_ + 0.5f * b_;
            const float cr = 0.5f * r_ + (float)(-0.418687589) * g_ + (float)(-0.081312411) * b_;
            yv[k]  = clip01(y) - OFF;
            cbv[k] = clip01(cb + OFF);     // clipped, pre-subtract (subtract after pool)
            crv[k] = clip01(cr + OFF);
        }
        // transposed Y writes: column c holds Y[r][c] at YTT + c*36 + r
        *(float2*)&smem[YTT + c0 * 36 + r0]       = make_float2(yv[0], yv[2]);
        *(float2*)&smem[YTT + (c0 + 1) * 36 + r0] = make_float2(yv[1], yv[3]);
        // in-register pool, exact reference order ((w00+w01)+w10)+w11, then -OFF
        float sb = cbv[0];
        sb = sb + cbv[1];
        sb = sb + cbv[2];
        sb = sb + cbv[3];
        smem[CBT + qc * 20 + qr] = sb * 0.25f - OFF;
        float sr = crv[0];
        sr = sr + crv[1];
        sr = sr + crv[2];
        sr = sr + crv[3];
        smem[CRT + qc * 20 + qr] = sr * 0.25f - OFF;
    }
    __syncthreads();

    // ---- DCT + quantize: 8 threads per 8x8 block, one pass ----
    const int w  = t >> 6;           // wave 0..3
    const int l  = t & 63;
    const int bi = l >> 3;           // block-in-wave 0..5 (6,7 idle)
    const int lc = l & 7;            // stage-1 column / stage-2 row

    if (bi < 6) {
        const int sb = w * 6 + bi;   // block 0..23
        int xaddr, ch; size_t obase;
        if (sb < 16) {               // Y: 4x4 grid of 8x8 in the 32x32 tile
            const int sr = sb >> 2, sc = sb & 3;
            xaddr = YTT + (sc * 8 + lc) * 36 + sr * 8; ch = 0;
            obase = (((size_t)(b * 64 + th * 4 + sr)) * 64 + (tw * 4 + sc)) * 64;
        } else if (sb < 20) {        // Cb: 2x2 grid in pooled 16x16
            const int s = sb - 16, sr = s >> 1, sc = s & 1;
            xaddr = CBT + (sc * 8 + lc) * 20 + sr * 8; ch = 1;
            obase = (size_t)4194304 + (((size_t)(b * 32 + th * 2 + sr)) * 32 + (tw * 2 + sc)) * 64;
        } else {                     // Cr
            const int s = sb - 20, sr = s >> 1, sc = s & 1;
            xaddr = CRT + (sc * 8 + lc) * 20 + sr * 8; ch = 2;
            obase = (size_t)5242880 + (((size_t)(b * 32 + th * 2 + sr)) * 32 + (tw * 2 + sc)) * 64;
        }

        // stage 1: thread owns column lc; X column is contiguous (transposed
        // layout) -> 2x ds_read_b128. T[i] = sum_j D[i][j] * X[j][lc],
        // j-ascending fmac chain as in the bit-exact round-8 kernel.
        float x[8];
        *(float4*)&x[0] = *(const float4*)&smem[xaddr];
        *(float4*)&x[4] = *(const float4*)&smem[xaddr + 4];
        const int tbase = TMP + w * 408 + bi * 68;   // 68-dword pad, 16B-aligned
        #pragma unroll
        for (int i = 0; i < 8; ++i) {
            float s = 0.0f;
            #pragma unroll
            for (int j = 0; j < 8; ++j) s += Dm[i][j] * x[j];
            smem[tbase + i * 8 + lc] = s;
        }

        // stage 2: thread owns row lc of T (written by the 8 column-threads of
        // this block; intra-wave LDS ops complete in order -> no barrier,
        // validated bit-exact in rounds 7-8).
        float tr[8], q[8];
        *(float4*)&tr[0] = *(const float4*)&smem[tbase + lc * 8];
        *(float4*)&tr[4] = *(const float4*)&smem[tbase + lc * 8 + 4];
        *(float4*)&q[0]  = *(const float4*)&smem[QNT + ch * 64 + lc * 8];
        *(float4*)&q[4]  = *(const float4*)&smem[QNT + ch * 64 + lc * 8 + 4];

        const float qadd = (float)(0.5 / 255.0);
        float o[8];
        #pragma unroll
        for (int cc = 0; cc < 8; ++cc) {
            float s = 0.0f;
            #pragma unroll
            for (int k = 0; k < 8; ++k) s += tr[k] * Dm[cc][k];   // k-ascending, as before
            const float den = __fadd_rn(__fmul_rn(q[cc], 2.5f), qadd);
            o[cc] = rintf(s / den);      // IEEE div + round-half-even, matches np
        }
        float* op = out + obase + lc * 8;
        *(float4*)&op[0] = make_float4(o[0], o[1], o[2], o[3]);
        *(float4*)&op[4] = make_float4(o[4], o[5], o[6], o[7]);
    }
}

extern "C" void kernel_launch(void* const* d_in, const int* in_sizes, int n_in,
                              void* d_out, int out_size, void* d_ws, size_t ws_size,
                              hipStream_t stream) {
    const float* rgb   = (const float*)d_in[0];
    const float* quant = (const float*)d_in[1];
    float* out = (float*)d_out;
    dim3 grid(4096), block(256);
    hipLaunchKernelGGL(jpeg_kernel, grid, block, 0, stream, rgb, quant, out);
}